// Round 1
// baseline (186.656 us; speedup 1.0000x reference)
//
#include <hip/hip_runtime.h>
#include <math.h>

#define EPS 1e-6f
#define TAU 1.0f

// Full per-box loss, scalar inputs. Same math as the verified v1 kernel
// (passed absmax 3.9e-3 with __sincosf/__logf/__frcp_rn).
__device__ __forceinline__ float box_loss(float px, float py, float pw, float ph, float pr,
                                          float tx, float ty, float tw, float th, float tr) {
    pw = fminf(fmaxf(pw, 1e-7f), 1e7f);
    ph = fminf(fmaxf(ph, 1e-7f), 1e7f);
    tw = fminf(fmaxf(tw, 1e-7f), 1e7f);
    th = fminf(fmaxf(th, 1e-7f), 1e7f);

    float pa = 0.25f * pw * pw, pb = 0.25f * ph * ph;
    float ta = 0.25f * tw * tw, tb = 0.25f * th * th;

    float ps, pc, ts, tc;
    __sincosf(pr, &ps, &pc);
    __sincosf(tr, &ts, &tc);

    float p11 = pa * pc * pc + pb * ps * ps;
    float p12 = (pa - pb) * ps * pc;
    float p22 = pa * ps * ps + pb * pc * pc;
    float t11 = ta * tc * tc + tb * ts * ts;
    float t12 = (ta - tb) * ts * tc;
    float t22 = ta * ts * ts + tb * tc * tc;

    float det_p = p11 * p22 - p12 * p12;
    float det_t = t11 * t22 - t12 * t12;

    float dx = px - tx;
    float dy = py - ty;

    float inv_det_t = __frcp_rn(det_t);
    float term1 = (t22 * dx * dx - 2.0f * t12 * dx * dy + t11 * dy * dy) * inv_det_t;
    float trace_term = (t22 * p11 - 2.0f * t12 * p12 + t11 * p22) * inv_det_t;
    float term2 = trace_term + __logf(det_t) - __logf(det_p);

    float dis = term1 + term2 - 2.0f;
    float kl = fmaxf(dis, EPS);
    return 1.0f - __frcp_rn(TAU + sqrtf(kl));
}

// 4 boxes per thread: 4 boxes x 5 floats = 5 aligned float4 loads per array,
// one float4 store. 11 VMEM instructions per 4 boxes instead of 44.
__global__ void __launch_bounds__(256) gd_loss_kernel4(
        const float4* __restrict__ pred4,
        const float4* __restrict__ tgt4,
        float4* __restrict__ out4, int n4) {
    int i = blockIdx.x * blockDim.x + threadIdx.x;
    if (i >= n4) return;

    const float4* p = pred4 + (size_t)i * 5;   // 80 B per thread -> 16 B aligned
    const float4* t = tgt4  + (size_t)i * 5;

    float4 a0 = p[0], a1 = p[1], a2 = p[2], a3 = p[3], a4 = p[4];
    float4 b0 = t[0], b1 = t[1], b2 = t[2], b3 = t[3], b4 = t[4];

    float4 r;
    r.x = box_loss(a0.x, a0.y, a0.z, a0.w, a1.x,
                   b0.x, b0.y, b0.z, b0.w, b1.x);
    r.y = box_loss(a1.y, a1.z, a1.w, a2.x, a2.y,
                   b1.y, b1.z, b1.w, b2.x, b2.y);
    r.z = box_loss(a2.z, a2.w, a3.x, a3.y, a3.z,
                   b2.z, b2.w, b3.x, b3.y, b3.z);
    r.w = box_loss(a3.w, a4.x, a4.y, a4.z, a4.w,
                   b3.w, b4.x, b4.y, b4.z, b4.w);

    out4[i] = r;
}

// Scalar tail for n % 4 boxes (not hit at N = 4,000,000; defensive).
__global__ void __launch_bounds__(64) gd_loss_tail(
        const float* __restrict__ pred,
        const float* __restrict__ tgt,
        float* __restrict__ out, int start, int n) {
    int i = start + blockIdx.x * blockDim.x + threadIdx.x;
    if (i >= n) return;
    const float* p = pred + (size_t)i * 5;
    const float* t = tgt  + (size_t)i * 5;
    out[i] = box_loss(p[0], p[1], p[2], p[3], p[4],
                      t[0], t[1], t[2], t[3], t[4]);
}

extern "C" void kernel_launch(void* const* d_in, const int* in_sizes, int n_in,
                              void* d_out, int out_size, void* d_ws, size_t ws_size,
                              hipStream_t stream) {
    const float* pred = (const float*)d_in[0];
    const float* tgt  = (const float*)d_in[1];
    float* out = (float*)d_out;
    int n = out_size;  // N boxes, one loss per box

    int n4 = n >> 2;
    int rem = n & 3;

    if (n4 > 0) {
        int block = 256;
        int grid = (n4 + block - 1) / block;
        gd_loss_kernel4<<<grid, block, 0, stream>>>(
            (const float4*)pred, (const float4*)tgt, (float4*)out, n4);
    }
    if (rem > 0) {
        gd_loss_tail<<<1, 64, 0, stream>>>(pred, tgt, out, n4 << 2, n);
    }
}